// Round 10
// baseline (332.986 us; speedup 1.0000x reference)
//
#include <hip/hip_runtime.h>

// GatedRecurrentCell: B=8 S=2048 D=512 I=2048. M=B*S=16384, N2=2*I=4096, K=D=512.
// R10: SPLIT the fused gate epilogue out of the GEMM. Evidence: 6 K-loop
// variants (conflicts/barriers/fastmath/vmcnt/XCD/256^2-tile) all pin gemm at
// 146-170us while K-loop resources sum to ~35us -> the untouched fused epilogue
// (LDS C-stage + 2 barriers/round + serial gate_ac + 4B scalar AC stores) is
// the prime suspect. New structure:
//   gemm_pp:  K-loop (R9-proven 256^2 2-phase + swizzle) + frag-native pa/pi
//             store (8B/lane contiguous, no LDS, no barriers, no gate math).
//   gate_agg: PP -> 32-step chunk aggregates (A,H). Streaming, f16x8 loads
//             (frag-native: one 16B load = 4 rows of one (pa,pi) column pair).
//   scan_pass2: unchanged (chunk-carry scan).
//   scan_out: PP + carry -> out, gate_ac computed inline in the fma replay
//             (VALU hides under BW). AC buffer eliminated.
// PP frag-native layout: PP[(by*16+bx)<<16 | wave*8192 | i*1024 | j*256 |
// lane*4 | rr], m = by*256 + (wave&1)*128 + i*16 + (lane>>4)*4 + rr,
// n = bx*256 + (wave>>1)*64 + j*16 + (lane&15). Lane-pairs = column-pairs.
// ws: [0,16Mi) x_f16 | [16,20Mi) W_f16 | [20Mi,+128Mi) PP f16 | +8Mi agg | +4Mi carry

#define LOG2_3 1.5849625007211562f

typedef _Float16 f16x8 __attribute__((ext_vector_type(8)));
typedef _Float16 f16x4 __attribute__((ext_vector_type(4)));
typedef _Float16 f16x2 __attribute__((ext_vector_type(2)));
typedef float f32x4 __attribute__((ext_vector_type(4)));

__device__ __forceinline__ float sigmoid_fast(float v) {
  return __fdividef(1.0f, 1.0f + __expf(-v));
}

__device__ __forceinline__ void async_copy16(void* lds, const void* gp) {
  __builtin_amdgcn_global_load_lds((__attribute__((address_space(1))) void*)gp,
                                   (__attribute__((address_space(3))) void*)lds,
                                   16, 0, 0);
}

// x -> xh (plain). Wa/Wi -> wh with row interleave: wh row 2i = Wa_i, 2i+1 = Wi_i.
__global__ __launch_bounds__(256) void cvt_all(const float* __restrict__ x,
                                               const float* __restrict__ Wa,
                                               const float* __restrict__ Wi,
                                               _Float16* __restrict__ xh,
                                               _Float16* __restrict__ wh) {
  int idx = blockIdx.x * 256 + threadIdx.x;
  const float* src;
  _Float16* dst;
  int off, doff;
  if (idx < 2097152) {
    src = x; dst = xh; off = idx; doff = idx;
  } else if (idx < 2097152 + 262144) {
    src = Wa; dst = wh; off = idx - 2097152;
    doff = off + ((off >> 7) << 7);          // (2i)*128 + k4
  } else {
    src = Wi; dst = wh; off = idx - 2359296;
    doff = off + ((off >> 7) << 7) + 128;    // (2i+1)*128 + k4
  }
  float4 v = ((const float4*)src)[off];
  f16x4 h;
  h[0] = (_Float16)v.x;
  h[1] = (_Float16)v.y;
  h[2] = (_Float16)v.z;
  h[3] = (_Float16)v.w;
  ((f16x4*)dst)[doff] = h;
}

__device__ __forceinline__ void gate_ac(float pa, float pi, float alpha, float& a, float& c) {
  float rg = sigmoid_fast(pa);
  a = alpha * exp2f(-LOG2_3 * rg);
  float ig = sigmoid_fast(pi);
  float m = fmaxf(1.0f - a * a, 1e-8f);
  c = (m * __frsqrt_rn(m)) * (ig * pi);  // sqrt(m) = m * rsqrt(m)
}

// GEMM 256x256 tile, 8 waves, K-loop identical to R9 (2-phase, XOR swizzle).
// Epilogue: bias + f16 cvt + frag-native stores (32 x 8B/thread). No LDS reuse,
// no barriers, no transcendentals.
__global__ __launch_bounds__(512) void gemm_pp(const _Float16* __restrict__ Ah,
                                               const _Float16* __restrict__ Wh,
                                               const float* __restrict__ ba,
                                               const float* __restrict__ bi,
                                               _Float16* __restrict__ PP) {
  constexpr int K = 512;
  __shared__ __align__(16) _Float16 smem[32768];  // 64 KiB: 2 x 32KB K-buffers
  const int t = threadIdx.x;
  const int bx = blockIdx.x;  // 0..15 (n)
  const int by = blockIdx.y;  // 0..63 (m)
  const int mBase = by * 256;
  const int nBase = bx * 256;
  const int r = t >> 2;                      // staged row 0..127 (+128 for 2nd)
  const int p = t & 3;                       // physical 16B slot
  const int lsw = p ^ ((r >> 1) & 3);        // pre-swizzled source slot
  const _Float16* gA0 = Ah + (size_t)(mBase + r) * K + lsw * 8;
  const _Float16* gB0 = Wh + (size_t)(nBase + r) * K + lsw * 8;
  const int ldst = r * 32 + p * 8;           // byte off == t*16 (linear)

  const int lane = t & 63;
  const int wave = t >> 6;                   // 0..7
  const int wm = (wave & 1) * 128;
  const int wn = (wave >> 1) * 64;
  const int lrow = lane & 15;
  const int quad = lane >> 4;
  const int xq = quad ^ ((lrow >> 1) & 3);   // read-side swizzle

  f32x4 acc[8][4];
#pragma unroll
  for (int i = 0; i < 8; ++i)
#pragma unroll
    for (int j = 0; j < 4; ++j)
      acc[i][j] = (f32x4)0.0f;

  _Float16* b0 = smem;
  _Float16* b1 = smem + 16384;

  auto STAGE = [&](int tt, _Float16* bb) {
    const int ko = tt * 32;
    async_copy16(bb + ldst, gA0 + ko);                            // A rows 0-127
    async_copy16(bb + 4096 + ldst, gA0 + (size_t)128 * K + ko);   // A rows 128-255
    async_copy16(bb + 8192 + ldst, gB0 + ko);                     // B rows 0-127
    async_copy16(bb + 12288 + ldst, gB0 + (size_t)128 * K + ko);  // B rows 128-255
  };

  STAGE(0, b0);
  __syncthreads();

#pragma unroll
  for (int kt = 0; kt < 16; ++kt) {
    _Float16* cur = (kt & 1) ? b1 : b0;
    _Float16* nxt = (kt & 1) ? b0 : b1;
    if (kt < 15) STAGE(kt + 1, nxt);  // issue BEFORE compute; lands by next barrier
    f16x8 af[8], bf[4];
#pragma unroll
    for (int i = 0; i < 8; ++i)
      af[i] = *(const f16x8*)(cur + (wm + i * 16 + lrow) * 32 + xq * 8);
#pragma unroll
    for (int j = 0; j < 4; ++j)
      bf[j] = *(const f16x8*)(cur + 8192 + (wn + j * 16 + lrow) * 32 + xq * 8);
#pragma unroll
    for (int i = 0; i < 8; ++i)
#pragma unroll
      for (int j = 0; j < 4; ++j)
        acc[i][j] = __builtin_amdgcn_mfma_f32_16x16x32_f16(af[i], bf[j], acc[i][j], 0, 0, 0);
    __syncthreads();  // single barrier/K-step
  }

  // bias: col n even -> ba[n/2] (pa), odd -> bi[n/2] (pi)
  float bias[4];
#pragma unroll
  for (int j = 0; j < 4; ++j) {
    const int n = nBase + wn + j * 16 + lrow;
    bias[j] = (n & 1) ? bi[n >> 1] : ba[n >> 1];
  }

  // frag-native store: lane's 4 rr values contiguous (8B), wave = 512B/frag.
  _Float16* pp = PP + (((size_t)by * 16 + bx) << 16) + wave * 8192 + lane * 4;
#pragma unroll
  for (int i = 0; i < 8; ++i)
#pragma unroll
    for (int j = 0; j < 4; ++j) {
      f16x4 v;
#pragma unroll
      for (int rr = 0; rr < 4; ++rr)
        v[rr] = (_Float16)(acc[i][j][rr] + bias[j]);
      *(f16x4*)(pp + i * 1024 + j * 256) = v;
    }
}

// PP -> 32-step chunk aggregates (A = prod a, H = fold a*H+c), s-ascending.
// Thread owns column-pair tt (cols 2tt,2tt+1) x chunk ch x batch b.
// One f16x8 load = 4 rows of (pa,pi) for this pair (lane even, lane+1 odd).
__global__ __launch_bounds__(256) void gate_agg(const _Float16* __restrict__ PP,
                                                const float* __restrict__ gate,
                                                float2* __restrict__ agg) {
  const int tt = blockIdx.x * 256 + threadIdx.x;  // 0..2047
  const int ch = blockIdx.y;                      // 0..63
  const int b = blockIdx.z;                       // 0..7
  const float alpha = sigmoid_fast(gate[tt]);
  const int n = tt * 2;
  const int bx = n >> 8;
  const int nl = n & 255;
  const int wn_idx = nl >> 6;
  const int j = (nl >> 4) & 3;
  const int lrow = nl & 15;                       // even
  const int by = b * 8 + (ch >> 3);
  const int c8 = ch & 7;
  const int wm_bit = c8 >> 2;
  const _Float16* base = PP + (((size_t)by * 16 + bx) << 16) +
                         (wm_bit + 2 * wn_idx) * 8192 + j * 256 + lrow * 4;
  f16x8 v[8];
#pragma unroll
  for (int u = 0; u < 8; ++u) {
    const int i = (c8 * 2 + (u >> 2)) & 7;  // s = (u>>2)*16 + (u&3)*4 + rr
    v[u] = *(const f16x8*)(base + i * 1024 + (u & 3) * 64);
  }
  float A = 1.0f, H = 0.0f;
#pragma unroll
  for (int u = 0; u < 8; ++u)
#pragma unroll
    for (int rr = 0; rr < 4; ++rr) {
      float a, c;
      gate_ac((float)v[u][rr], (float)v[u][4 + rr], alpha, a, c);
      A *= a;
      H = fmaf(a, H, c);
    }
  agg[((size_t)(b * 64 + ch)) * 2048 + tt] = make_float2(A, H);
}

__global__ __launch_bounds__(64) void scan_pass2(const float2* __restrict__ agg,
                                                 float* __restrict__ carry) {
  const int i = blockIdx.x * 64 + threadIdx.x;  // grid.x=32 -> 0..2047
  const int b = blockIdx.y;
  float h = 0.0f;
  for (int c8 = 0; c8 < 8; ++c8) {
    float2 aH[8];
#pragma unroll
    for (int u = 0; u < 8; ++u)
      aH[u] = agg[((size_t)(b * 64 + c8 * 8 + u)) * 2048 + i];
#pragma unroll
    for (int u = 0; u < 8; ++u) {
      carry[((size_t)(b * 64 + c8 * 8 + u)) * 2048 + i] = h;
      h = fmaf(aH[u].x, h, aH[u].y);
    }
  }
}

// Replay with inline gate: h = a*h + c from f16 pa/pi (same values gate_agg
// used -> consistent). Thread owns column tt, chunk ch, batch b; 32 steps.
__global__ __launch_bounds__(256) void scan_out(const _Float16* __restrict__ PP,
                                                const float* __restrict__ gate,
                                                const float* __restrict__ carry,
                                                float* __restrict__ out) {
  const int tt = blockIdx.x * 256 + threadIdx.x;  // 0..2047
  const int ch = blockIdx.y;                      // 0..63
  const int b = blockIdx.z;                       // 0..7
  const float alpha = sigmoid_fast(gate[tt]);
  float h = carry[((size_t)(b * 64 + ch)) * 2048 + tt];
  const int n = tt * 2;
  const int bx = n >> 8;
  const int nl = n & 255;
  const int wn_idx = nl >> 6;
  const int j = (nl >> 4) & 3;
  const int lrow = nl & 15;
  const int by = b * 8 + (ch >> 3);
  const int c8 = ch & 7;
  const int wm_bit = c8 >> 2;
  const _Float16* base = PP + (((size_t)by * 16 + bx) << 16) +
                         (wm_bit + 2 * wn_idx) * 8192 + j * 256 + lrow * 4;
  f16x8 v[8];
#pragma unroll
  for (int u = 0; u < 8; ++u) {
    const int i = (c8 * 2 + (u >> 2)) & 7;
    v[u] = *(const f16x8*)(base + i * 1024 + (u & 3) * 64);
  }
  float* orow = out + ((size_t)(b * 2048 + ch * 32)) * 2048 + tt;
#pragma unroll
  for (int u = 0; u < 8; ++u)
#pragma unroll
    for (int rr = 0; rr < 4; ++rr) {
      float a, c;
      gate_ac((float)v[u][rr], (float)v[u][4 + rr], alpha, a, c);
      h = fmaf(a, h, c);
      __builtin_nontemporal_store(h, orow);
      orow += 2048;
    }
}

extern "C" void kernel_launch(void* const* d_in, const int* in_sizes, int n_in,
                              void* d_out, int out_size, void* d_ws, size_t ws_size,
                              hipStream_t stream) {
  const float* x = (const float*)d_in[0];
  const float* Wa = (const float*)d_in[1];
  const float* ba = (const float*)d_in[2];
  const float* Wi = (const float*)d_in[3];
  const float* bi = (const float*)d_in[4];
  const float* gate = (const float*)d_in[5];
  float* out = (float*)d_out;

  char* ws = (char*)d_ws;
  _Float16* xh = (_Float16*)ws;               // 16 MiB
  _Float16* wh = (_Float16*)(ws + 16777216);  // 4 MiB (interleaved Wa/Wi)
  const size_t MN2 = (size_t)16384 * 4096;
  _Float16* PP = (_Float16*)(ws + 20971520);  // 128 MiB pa/pi frag-native
  float2* agg = (float2*)(ws + 20971520 + MN2 * 2);            // 8 MiB
  float* carry = (float*)(ws + 20971520 + MN2 * 2 + 8388608);  // 4 MiB

  cvt_all<<<10240, 256, 0, stream>>>(x, Wa, Wi, xh, wh);
  gemm_pp<<<dim3(16, 64), 512, 0, stream>>>(xh, wh, ba, bi, PP);
  gate_agg<<<dim3(8, 64, 8), 256, 0, stream>>>(PP, gate, agg);
  scan_pass2<<<dim3(32, 8), 64, 0, stream>>>(agg, carry);
  scan_out<<<dim3(8, 64, 8), 256, 0, stream>>>(PP, gate, carry, out);
}